// Round 4
// baseline (515.062 us; speedup 1.0000x reference)
//
#include <hip/hip_runtime.h>
#include <hip/hip_bf16.h>
#include <math.h>

// ---------------------------------------------------------------------------
// ChunkGatedAttentionUnit: B=2, S=4096, H=1024, D=2048, CHUNK=128, nC=32
// Round 4: attack HBM traffic (measured 9x ideal on qkvg):
//   - nontemporal stores on all big output streams (no RFO, no L3 eviction)
//   - qkvg block mapping: 16x16 super-rounds, XCD-chunked nb
// GEMM cores unchanged from round 3.
// ---------------------------------------------------------------------------

typedef __bf16 bf16_t;
typedef __bf16 bf16x8 __attribute__((ext_vector_type(8)));
typedef __bf16 bf16x4 __attribute__((ext_vector_type(4)));
typedef float f32x4 __attribute__((ext_vector_type(4)));

#define NB_ 2
#define SEQ 4096
#define HID 1024
#define DD 2048
#define BS 8192
#define LDS256 131072
#define LDS128 98304

__device__ __forceinline__ void async16(const void* g, void* l) {
  __builtin_amdgcn_global_load_lds(
      (const __attribute__((address_space(1))) void*)g,
      (__attribute__((address_space(3))) void*)l, 16, 0, 0);
}

#define VMW(n) asm volatile("s_waitcnt vmcnt(" #n ")" ::: "memory")
#define BARR __builtin_amdgcn_s_barrier()
#define FEN asm volatile("" ::: "memory")
#define NTS(p, v) __builtin_nontemporal_store((v), (p))

template <int MFH>
__device__ __forceinline__ void readA8(const bf16_t* bufA, int aBase, int s0, int s1,
                                       bf16x8 (&af)[4][2]) {
#pragma unroll
  for (int mm = 0; mm < 4; ++mm) {
    int p = aBase + MFH * 8192 + mm * 1024;
    af[mm][0] = *reinterpret_cast<const bf16x8*>(&bufA[p + s0]);
    af[mm][1] = *reinterpret_cast<const bf16x8*>(&bufA[p + s1]);
  }
}
template <int NFH>
__device__ __forceinline__ void readB4(const bf16_t* bufB, int bBase, int s0, int s1,
                                       bf16x8 (&bv)[2][2]) {
#pragma unroll
  for (int nn = 0; nn < 2; ++nn) {
    int p = bBase + NFH * 8192 + nn * 1024;
    bv[nn][0] = *reinterpret_cast<const bf16x8*>(&bufB[p + s0]);
    bv[nn][1] = *reinterpret_cast<const bf16x8*>(&bufB[p + s1]);
  }
}
template <int MROWS, int MQ, int NQ>
__device__ __forceinline__ void mfmaQ(const bf16x8 (&af)[4][2], const bf16x8 (&bv)[2][2],
                                      f32x4 (&acc)[MROWS][4]) {
  __builtin_amdgcn_s_setprio(1);
#pragma unroll
  for (int kki = 0; kki < 2; ++kki)
#pragma unroll
    for (int mm = 0; mm < 4; ++mm)
#pragma unroll
      for (int nn = 0; nn < 2; ++nn)
        acc[MQ * 4 + mm][NQ * 2 + nn] = __builtin_amdgcn_mfma_f32_16x16x32_bf16(
            af[mm][kki], bv[nn][kki], acc[MQ * 4 + mm][NQ * 2 + nn], 0, 0, 0);
  __builtin_amdgcn_s_setprio(0);
}

// ---- BM=256 x BN=256 core, BK=64, 8 waves (2Mx4N), per-wave 128x64 --------
__device__ __forceinline__ void core256(const bf16_t* __restrict__ A, int lda,
                                        const bf16_t* __restrict__ B, int ldb, int nt,
                                        bf16_t* lds, f32x4 (&acc)[8][4]) {
  const int t = threadIdx.x;
  const int lane = t & 63, w = t >> 6;
  const int wm = w >> 2, wn = w & 3;
  const int lr = lane & 15, lg = lane >> 4;
  const int xm = lr & 7;
  const int aBase = (wm * 64 + lr) * 64;
  const int bBase = (wn * 32 + lr) * 64;
  const int s0 = (lg ^ xm) * 8, s1 = ((4 + lg) ^ xm) * 8;
  const int slog = ((t & 7) ^ ((t >> 3) & 7)) * 8;
  int srcA[4], srcB[4];
#pragma unroll
  for (int blk = 0; blk < 4; ++blk) {
    int rA = ((blk & 1) << 7) + ((blk >> 1) << 6) + (t >> 3);
    int prB = (blk << 6) + (t >> 3);
    int rB = (((prB >> 5) & 3) << 6) + ((prB >> 7) << 5) + (prB & 31);
    srcA[blk] = rA * lda + slog;
    srcB[blk] = rB * ldb + slog;
  }
  const int dstT = t * 8;
#pragma unroll
  for (int m = 0; m < 8; ++m)
#pragma unroll
    for (int n = 0; n < 4; ++n) acc[m][n] = (f32x4){0.f, 0.f, 0.f, 0.f};

  {  // prologue: stage tile 0; order A0,A1,B0,B1,A2,A3,B2,B3
    bf16_t* nA = lds;
    bf16_t* nB = lds + 16384;
    async16(A + srcA[0], nA + dstT);
    async16(A + srcA[1], nA + 4096 + dstT);
    async16(B + srcB[0], nB + dstT);
    async16(B + srcB[1], nB + 4096 + dstT);
    async16(A + srcA[2], nA + 8192 + dstT);
    async16(A + srcA[3], nA + 12288 + dstT);
    async16(B + srcB[2], nB + 8192 + dstT);
    async16(B + srcB[3], nB + 12288 + dstT);
  }
  bf16x8 af0[4][2], af1[4][2], bv0[2][2], bv1[2][2];
  for (int kt = 0; kt < nt; ++kt) {
    bf16_t* bufA = lds + ((kt & 1) << 15);
    bf16_t* bufB = bufA + 16384;
    bf16_t* nA = lds + (((kt + 1) & 1) << 15);
    bf16_t* nB = nA + 16384;
    const int kn = (kt + 1 < nt ? kt + 1 : 0) << 6;
    const bf16_t* An = A + kn;
    const bf16_t* Bn = B + kn;
    VMW(2); BARR; FEN;
    readA8<0>(bufA, aBase, s0, s1, af0);
    readB4<0>(bufB, bBase, s0, s1, bv0);
    readA8<1>(bufA, aBase, s0, s1, af1);
    async16(An + srcA[0], nA + dstT);
    async16(An + srcA[1], nA + 4096 + dstT);
    mfmaQ<8, 0, 0>(af0, bv0, acc);
    VMW(2); BARR; FEN;
    readB4<1>(bufB, bBase, s0, s1, bv1);
    async16(Bn + srcB[0], nB + dstT);
    async16(Bn + srcB[1], nB + 4096 + dstT);
    mfmaQ<8, 1, 0>(af1, bv0, acc);
    async16(An + srcA[2], nA + 8192 + dstT);
    async16(An + srcA[3], nA + 12288 + dstT);
    mfmaQ<8, 1, 1>(af1, bv1, acc);
    async16(Bn + srcB[2], nB + 8192 + dstT);
    async16(Bn + srcB[3], nB + 12288 + dstT);
    mfmaQ<8, 0, 1>(af0, bv1, acc);
  }
  VMW(0);
  BARR;
}

// ---- BM=128 x BN=256 core, BK=64, 8 waves (2Mx4N), per-wave 64x64 ---------
__device__ __forceinline__ void core128(const bf16_t* __restrict__ A, int lda,
                                        const bf16_t* __restrict__ B, int ldb, int nt,
                                        bf16_t* lds, f32x4 (&acc)[4][4]) {
  const int t = threadIdx.x;
  const int lane = t & 63, w = t >> 6;
  const int wm = w >> 2, wn = w & 3;
  const int lr = lane & 15, lg = lane >> 4;
  const int xm = lr & 7;
  const int aBase = (wm * 64 + lr) * 64;
  const int bBase = (wn * 32 + lr) * 64;
  const int s0 = (lg ^ xm) * 8, s1 = ((4 + lg) ^ xm) * 8;
  const int slog = ((t & 7) ^ ((t >> 3) & 7)) * 8;
  int srcA[2], srcB[4];
#pragma unroll
  for (int blk = 0; blk < 2; ++blk) srcA[blk] = (blk * 64 + (t >> 3)) * lda + slog;
#pragma unroll
  for (int blk = 0; blk < 4; ++blk) {
    int prB = (blk << 6) + (t >> 3);
    int rB = (((prB >> 5) & 3) << 6) + ((prB >> 7) << 5) + (prB & 31);
    srcB[blk] = rB * ldb + slog;
  }
  const int dstT = t * 8;
#pragma unroll
  for (int m = 0; m < 4; ++m)
#pragma unroll
    for (int n = 0; n < 4; ++n) acc[m][n] = (f32x4){0.f, 0.f, 0.f, 0.f};

  {  // prologue: order A0,A1,B0,B1,B2,B3
    bf16_t* nA = lds;
    bf16_t* nB = lds + 8192;
    async16(A + srcA[0], nA + dstT);
    async16(A + srcA[1], nA + 4096 + dstT);
    async16(B + srcB[0], nB + dstT);
    async16(B + srcB[1], nB + 4096 + dstT);
    async16(B + srcB[2], nB + 8192 + dstT);
    async16(B + srcB[3], nB + 12288 + dstT);
  }
  bf16x8 af[4][2], bv0[2][2], bv1[2][2];
  for (int kt = 0; kt < nt; ++kt) {
    bf16_t* bufA = lds + (kt & 1) * 24576;
    bf16_t* bufB = bufA + 8192;
    bf16_t* nA = lds + ((kt + 1) & 1) * 24576;
    bf16_t* nB = nA + 8192;
    const int kn = (kt + 1 < nt ? kt + 1 : 0) << 6;
    const bf16_t* An = A + kn;
    const bf16_t* Bn = B + kn;
    VMW(2); BARR; FEN;
    readA8<0>(bufA, aBase, s0, s1, af);
    readB4<0>(bufB, bBase, s0, s1, bv0);
    async16(An + srcA[0], nA + dstT);
    async16(An + srcA[1], nA + 4096 + dstT);
    async16(Bn + srcB[0], nB + dstT);
    mfmaQ<4, 0, 0>(af, bv0, acc);
    VMW(3); BARR; FEN;
    readB4<1>(bufB, bBase, s0, s1, bv1);
    async16(Bn + srcB[1], nB + 4096 + dstT);
    async16(Bn + srcB[2], nB + 8192 + dstT);
    async16(Bn + srcB[3], nB + 12288 + dstT);
    mfmaQ<4, 0, 1>(af, bv1, acc);
  }
  VMW(0);
  BARR;
}

// --- elementwise convert f32 -> bf16 ---------------------------------------
__global__ void k_cvt(const float4* __restrict__ in, bf16x4* __restrict__ out, int n4) {
  int i = blockIdx.x * blockDim.x + threadIdx.x;
  if (i < n4) {
    float4 v = in[i];
    bf16x4 o;
    o[0] = (bf16_t)v.x; o[1] = (bf16_t)v.y; o[2] = (bf16_t)v.z; o[3] = (bf16_t)v.w;
    out[i] = o;
  }
}

// --- tiled transpose + convert f32[R][C] -> bf16[C][R] ----------------------
__global__ void k_tconv(const float* __restrict__ in, bf16_t* __restrict__ out,
                        int R, int C) {
  __shared__ bf16_t tile[64][65];
  int bc = blockIdx.x, br = blockIdx.y;
  int t = threadIdx.x;
  int c = t & 63, r0 = t >> 6;
#pragma unroll
  for (int rr = 0; rr < 64; rr += 4) {
    int r = rr + r0;
    tile[r][c] = (bf16_t)in[(long)(br * 64 + r) * C + bc * 64 + c];
  }
  __syncthreads();
#pragma unroll
  for (int rr = 0; rr < 64; rr += 4) {
    int r = rr + r0;
    out[(long)(bc * 64 + r) * R + br * 64 + c] = tile[c][r];
  }
}

// --- tiled transpose bf16[R][C] -> bf16[C][R], per batch (z) ----------------
__global__ void k_tbf16(const bf16_t* __restrict__ in, bf16_t* __restrict__ out,
                        int R, int C) {
  __shared__ bf16_t tile[64][65];
  long zoff = (long)blockIdx.z * R * C;
  in += zoff;
  out += zoff;
  int bc = blockIdx.x, br = blockIdx.y;
  int t = threadIdx.x;
  int c = t & 63, r0 = t >> 6;
#pragma unroll
  for (int rr = 0; rr < 64; rr += 4) {
    int r = rr + r0;
    tile[r][c] = in[(long)(br * 64 + r) * C + bc * 64 + c];
  }
  __syncthreads();
#pragma unroll
  for (int rr = 0; rr < 64; rr += 4) {
    int r = rr + r0;
    out[(long)(bc * 64 + r) * R + br * 64 + c] = tile[c][r];
  }
}

// --- GEMM1: QKVG = hsb @ Wt^T + bias (sigmoid z==3), BM=256 ----------------
__global__ __launch_bounds__(512, 2) void k_gemm_qkvg(
    const bf16_t* __restrict__ hsb, const bf16_t* __restrict__ Wt4,
    const float* __restrict__ bq, const float* __restrict__ bk,
    const float* __restrict__ bv, const float* __restrict__ bg,
    bf16_t* __restrict__ out) {
  extern __shared__ bf16_t lds[];
  // 16x16 super-rounds, XCD-chunked nb: round q covers mb in [16(q&1),+16),
  // nb in [16(q>>1),+16); within a round each XCD owns a 16mb x 2nb slab.
  int c = blockIdx.x;
  int q = c >> 8, rr = c & 255;
  int xcd = rr & 7, j = rr >> 3;
  int mb = (q & 1) * 16 + (j & 15);
  int nb = (q >> 1) * 16 + ((xcd << 1) | (j >> 4));
  f32x4 acc[8][4];
  core256(hsb + (long)mb * 256 * HID, HID, Wt4 + (long)nb * 256 * HID, HID,
          HID / 64, lds, acc);
  const int t = threadIdx.x, lane = t & 63, w = t >> 6;
  const int wm = w >> 2, wn = w & 3, lr = lane & 15, lg = lane >> 4;
  int z = nb >> 3;
  const float* bias = z == 0 ? bq : z == 1 ? bk : z == 2 ? bv : bg;
  int colbase = (nb & 7) * 256 + wn * 64;
  float b4[4];
#pragma unroll
  for (int nf = 0; nf < 4; ++nf) b4[nf] = bias[colbase + nf * 16 + lr];
  bf16_t* O = out + (long)z * BS * DD;
#pragma unroll
  for (int mf = 0; mf < 8; ++mf)
#pragma unroll
    for (int reg = 0; reg < 4; ++reg) {
      long row = mb * 256 + wm * 128 + mf * 16 + lg * 4 + reg;
#pragma unroll
      for (int nf = 0; nf < 4; ++nf) {
        float v = acc[mf][nf][reg] + b4[nf];
        if (z == 3) v = 1.f / (1.f + __expf(-v));
        NTS(&O[row * DD + colbase + nf * 16 + lr], (bf16_t)v);
      }
    }
}

// --- pair: P[row-chunk c][jt-tile] = Q K^T; fused diag softmax, BM=128 ------
__global__ __launch_bounds__(512, 2) void k_pair(const bf16_t* __restrict__ Q,
                                                 const bf16_t* __restrict__ Kb,
                                                 bf16_t* __restrict__ P) {
  extern __shared__ bf16_t lds[];
  int p = blockIdx.x, b = blockIdx.y;
  int c = 0, base = 0;
  while (base + (c >> 1) + 1 <= p) { base += (c >> 1) + 1; ++c; }
  int jt = p - base;  // jt in [0, (c>>1)]
  f32x4 acc[4][4];
  core128(Q + ((long)b * SEQ + (long)c * 128) * DD, DD,
          Kb + ((long)b * SEQ + (long)jt * 256) * DD, DD, DD / 64, lds, acc);
  const int t = threadIdx.x, lane = t & 63, w = t >> 6;
  const int wm = w >> 2, wn = w & 3, lr = lane & 15, lg = lane >> 4;
  bf16_t* Pt = P + ((long)b * SEQ + (long)c * 128) * (long)SEQ + (long)jt * 256;
  const bool hasDiag = (jt == (c >> 1));
  const int side = c & 1;
  const float scale = 0.02209708691207961f;  // 1/sqrt(2048)
  float* smf = (float*)lds;  // 64KB scratch; core quiesced LDS
#pragma unroll
  for (int mf = 0; mf < 4; ++mf)
#pragma unroll
    for (int reg = 0; reg < 4; ++reg) {
      int row = wm * 64 + mf * 16 + lg * 4 + reg;
#pragma unroll
      for (int nf = 0; nf < 4; ++nf) {
        int col = wn * 64 + nf * 16 + lr;
        float v = acc[mf][nf][reg];
        if (hasDiag && ((col >> 7) == side)) {
          int cc = col & 127;
          float sv = v * scale;
          smf[row * 128 + ((cc + row) & 127)] = (cc <= row) ? sv : -1e30f;
        } else {
          NTS(&Pt[(long)row * SEQ + col], (bf16_t)v);
        }
      }
    }
  if (hasDiag) {
    __syncthreads();
    if (t < 128) {
      int r = t;
      float mx = -1e30f;
      for (int cc = 0; cc <= r; ++cc) mx = fmaxf(mx, smf[r * 128 + ((cc + r) & 127)]);
      float s = 0.f;
      for (int cc = 0; cc <= r; ++cc) s += __expf(smf[r * 128 + ((cc + r) & 127)] - mx);
      float inv = 1.f / s;
      for (int cc = 0; cc < 128; ++cc) {
        float v = (cc <= r) ? __expf(smf[r * 128 + ((cc + r) & 127)] - mx) * inv : 0.f;
        NTS(&Pt[(long)r * SEQ + side * 128 + cc], (bf16_t)v);
      }
    }
  }
}

// --- GEMM2: OutPre = (P @ V[0:K]) * gate, BM=128, longest-first -------------
__global__ __launch_bounds__(512, 2) void k_gemm2(const bf16_t* __restrict__ P,
                                                  const bf16_t* __restrict__ Vt,
                                                  const bf16_t* __restrict__ G,
                                                  bf16_t* __restrict__ OutPre) {
  extern __shared__ bf16_t lds[];
  int bid = blockIdx.x;
  int mq = 31 - (bid >> 4);  // longest-first
  int r2 = bid & 15;
  int nb = r2 >> 1, b = r2 & 1;
  f32x4 acc[4][4];
  core128(P + ((long)b * SEQ + (long)mq * 128) * (long)SEQ, SEQ,
          Vt + (long)b * DD * SEQ + (long)nb * 256 * SEQ, SEQ, (mq + 1) * 2, lds, acc);
  const int t = threadIdx.x, lane = t & 63, w = t >> 6;
  const int wm = w >> 2, wn = w & 3, lr = lane & 15, lg = lane >> 4;
#pragma unroll
  for (int mf = 0; mf < 4; ++mf)
#pragma unroll
    for (int reg = 0; reg < 4; ++reg) {
      long row = (long)b * SEQ + (long)mq * 128 + wm * 64 + mf * 16 + lg * 4 + reg;
#pragma unroll
      for (int nf = 0; nf < 4; ++nf) {
        long idx = row * DD + nb * 256 + wn * 64 + nf * 16 + lr;
        float g = (float)G[idx];
        NTS(&OutPre[idx], (bf16_t)(acc[mf][nf][reg] * g));
      }
    }
}

// --- GEMM3: out = OutPre @ Wo + bo (f32 out), BM=128 ------------------------
__global__ __launch_bounds__(512, 2) void k_gemm3(const bf16_t* __restrict__ OutPre,
                                                  const bf16_t* __restrict__ Wot,
                                                  const float* __restrict__ bo,
                                                  float* __restrict__ out) {
  extern __shared__ bf16_t lds[];
  int mb = blockIdx.x >> 2, nb = blockIdx.x & 3;
  f32x4 acc[4][4];
  core128(OutPre + (long)mb * 128 * DD, DD, Wot + (long)nb * 256 * DD, DD,
          DD / 64, lds, acc);
  const int t = threadIdx.x, lane = t & 63, w = t >> 6;
  const int wm = w >> 2, wn = w & 3, lr = lane & 15, lg = lane >> 4;
  int colbase = nb * 256 + wn * 64;
  float b4[4];
#pragma unroll
  for (int nf = 0; nf < 4; ++nf) b4[nf] = bo[colbase + nf * 16 + lr];
#pragma unroll
  for (int mf = 0; mf < 4; ++mf)
#pragma unroll
    for (int reg = 0; reg < 4; ++reg) {
      long row = mb * 128 + wm * 64 + mf * 16 + lg * 4 + reg;
#pragma unroll
      for (int nf = 0; nf < 4; ++nf)
        NTS(&out[row * HID + colbase + nf * 16 + lr], acc[mf][nf][reg] + b4[nf]);
    }
}

extern "C" void kernel_launch(void* const* d_in, const int* in_sizes, int n_in,
                              void* d_out, int out_size, void* d_ws, size_t ws_size,
                              hipStream_t stream) {
  const float* hs = (const float*)d_in[0];
  const float* Wq = (const float*)d_in[1];
  const float* bq = (const float*)d_in[2];
  const float* Wk = (const float*)d_in[3];
  const float* bk = (const float*)d_in[4];
  const float* Wv = (const float*)d_in[5];
  const float* bv = (const float*)d_in[6];
  const float* Wg = (const float*)d_in[7];
  const float* bg = (const float*)d_in[8];
  const float* Wo = (const float*)d_in[9];
  const float* bo = (const float*)d_in[10];
  float* out = (float*)d_out;

  char* ws = (char*)d_ws;
  const size_t MB = 1024 * 1024;
  bf16_t* P = (bf16_t*)(ws);
  bf16_t* hsb = (bf16_t*)(ws);
  bf16_t* Wt4 = (bf16_t*)(ws + 16 * MB);
  bf16_t* Wot = (bf16_t*)(ws + 64 * MB);
  bf16_t* QKVG = (bf16_t*)(ws + 68 * MB);
  bf16_t* Vt = (bf16_t*)(ws + 196 * MB);

  bf16_t* Qb = QKVG;
  bf16_t* Kbuf = QKVG + (long)BS * DD;
  bf16_t* Vbuf = QKVG + 2l * BS * DD;
  bf16_t* Gbuf = QKVG + 3l * BS * DD;
  bf16_t* OutPre = Vbuf;  // V row-major dead after Vt built

  hipFuncSetAttribute((const void*)k_gemm_qkvg,
                      hipFuncAttributeMaxDynamicSharedMemorySize, LDS256);
  hipFuncSetAttribute((const void*)k_pair,
                      hipFuncAttributeMaxDynamicSharedMemorySize, LDS128);
  hipFuncSetAttribute((const void*)k_gemm2,
                      hipFuncAttributeMaxDynamicSharedMemorySize, LDS128);
  hipFuncSetAttribute((const void*)k_gemm3,
                      hipFuncAttributeMaxDynamicSharedMemorySize, LDS128);

  // 1. conversions
  k_cvt<<<(BS * HID / 4 + 255) / 256, 256, 0, stream>>>((const float4*)hs,
                                                        (bf16x4*)hsb, BS * HID / 4);
  k_tconv<<<dim3(DD / 64, HID / 64), 256, 0, stream>>>(Wq, Wt4 + 0l * DD * HID, HID, DD);
  k_tconv<<<dim3(DD / 64, HID / 64), 256, 0, stream>>>(Wk, Wt4 + 1l * DD * HID, HID, DD);
  k_tconv<<<dim3(DD / 64, HID / 64), 256, 0, stream>>>(Wv, Wt4 + 2l * DD * HID, HID, DD);
  k_tconv<<<dim3(DD / 64, HID / 64), 256, 0, stream>>>(Wg, Wt4 + 3l * DD * HID, HID, DD);
  k_tconv<<<dim3(HID / 64, DD / 64), 256, 0, stream>>>(Wo, Wot, DD, HID);

  // 2. QKVG projection
  k_gemm_qkvg<<<1024, 512, LDS256, stream>>>(hsb, Wt4, bq, bk, bv, bg, QKVG);

  // 3. V -> Vt [B][D][S]
  k_tbf16<<<dim3(DD / 64, SEQ / 64, NB_), 256, 0, stream>>>(Vbuf, Vt, SEQ, DD);

  // 4. pairwise scores + fused diag softmax
  k_pair<<<dim3(272, 2), 512, LDS128, stream>>>(Qb, Kbuf, P);

  // 5. PV + gate
  k_gemm2<<<512, 512, LDS128, stream>>>(P, Vt, Gbuf, OutPre);

  // 6. output projection
  k_gemm3<<<256, 512, LDS128, stream>>>(OutPre, Wot, bo, out);
}

// Round 6
// 446.602 us; speedup vs baseline: 1.1533x; 1.1533x over previous
//
#include <hip/hip_runtime.h>
#include <hip/hip_bf16.h>
#include <math.h>

// ---------------------------------------------------------------------------
// ChunkGatedAttentionUnit: B=2, S=4096, H=1024, D=2048, CHUNK=128, nC=32
// Round 6: R5's coalesced LDS-staged epilogues at R3/R4's correct LDS size.
//   - core128 double-buffer = 98304 B (48KB x 2). R5 under-allocated -> OOB.
//   - staged epilogue (full-line cached stores) for qkvg/pair/gemm2.
// ---------------------------------------------------------------------------

typedef __bf16 bf16_t;
typedef __bf16 bf16x8 __attribute__((ext_vector_type(8)));
typedef __bf16 bf16x4 __attribute__((ext_vector_type(4)));
typedef float f32x4 __attribute__((ext_vector_type(4)));

#define NB_ 2
#define SEQ 4096
#define HID 1024
#define DD 2048
#define BS 8192
#define LDS_CORE 98304  // core128 dbuf 2x(16KB A + 32KB B); staging 67584 fits
#define SP 264          // padded staging row stride (elems)

__device__ __forceinline__ void async16(const void* g, void* l) {
  __builtin_amdgcn_global_load_lds(
      (const __attribute__((address_space(1))) void*)g,
      (__attribute__((address_space(3))) void*)l, 16, 0, 0);
}

#define VMW(n) asm volatile("s_waitcnt vmcnt(" #n ")" ::: "memory")
#define BARR __builtin_amdgcn_s_barrier()
#define FEN asm volatile("" ::: "memory")

template <int MFH>
__device__ __forceinline__ void readA8(const bf16_t* bufA, int aBase, int s0, int s1,
                                       bf16x8 (&af)[4][2]) {
#pragma unroll
  for (int mm = 0; mm < 4; ++mm) {
    int p = aBase + MFH * 8192 + mm * 1024;
    af[mm][0] = *reinterpret_cast<const bf16x8*>(&bufA[p + s0]);
    af[mm][1] = *reinterpret_cast<const bf16x8*>(&bufA[p + s1]);
  }
}
template <int NFH>
__device__ __forceinline__ void readB4(const bf16_t* bufB, int bBase, int s0, int s1,
                                       bf16x8 (&bv)[2][2]) {
#pragma unroll
  for (int nn = 0; nn < 2; ++nn) {
    int p = bBase + NFH * 8192 + nn * 1024;
    bv[nn][0] = *reinterpret_cast<const bf16x8*>(&bufB[p + s0]);
    bv[nn][1] = *reinterpret_cast<const bf16x8*>(&bufB[p + s1]);
  }
}
template <int MROWS, int MQ, int NQ>
__device__ __forceinline__ void mfmaQ(const bf16x8 (&af)[4][2], const bf16x8 (&bv)[2][2],
                                      f32x4 (&acc)[MROWS][4]) {
  __builtin_amdgcn_s_setprio(1);
#pragma unroll
  for (int kki = 0; kki < 2; ++kki)
#pragma unroll
    for (int mm = 0; mm < 4; ++mm)
#pragma unroll
      for (int nn = 0; nn < 2; ++nn)
        acc[MQ * 4 + mm][NQ * 2 + nn] = __builtin_amdgcn_mfma_f32_16x16x32_bf16(
            af[mm][kki], bv[nn][kki], acc[MQ * 4 + mm][NQ * 2 + nn], 0, 0, 0);
  __builtin_amdgcn_s_setprio(0);
}

// ---- BM=128 x BN=256 core, BK=64, 8 waves (2Mx4N), per-wave 64x64 ---------
// LDS: two buffers of 24576 elems each (A 8192 + B 16384) = 98304 B total.
__device__ __forceinline__ void core128(const bf16_t* __restrict__ A, int lda,
                                        const bf16_t* __restrict__ B, int ldb, int nt,
                                        bf16_t* lds, f32x4 (&acc)[4][4]) {
  const int t = threadIdx.x;
  const int lane = t & 63, w = t >> 6;
  const int wm = w >> 2, wn = w & 3;
  const int lr = lane & 15, lg = lane >> 4;
  const int xm = lr & 7;
  const int aBase = (wm * 64 + lr) * 64;
  const int bBase = (wn * 32 + lr) * 64;
  const int s0 = (lg ^ xm) * 8, s1 = ((4 + lg) ^ xm) * 8;
  const int slog = ((t & 7) ^ ((t >> 3) & 7)) * 8;
  int srcA[2], srcB[4];
#pragma unroll
  for (int blk = 0; blk < 2; ++blk) srcA[blk] = (blk * 64 + (t >> 3)) * lda + slog;
#pragma unroll
  for (int blk = 0; blk < 4; ++blk) {
    int prB = (blk << 6) + (t >> 3);
    int rB = (((prB >> 5) & 3) << 6) + ((prB >> 7) << 5) + (prB & 31);
    srcB[blk] = rB * ldb + slog;
  }
  const int dstT = t * 8;
#pragma unroll
  for (int m = 0; m < 4; ++m)
#pragma unroll
    for (int n = 0; n < 4; ++n) acc[m][n] = (f32x4){0.f, 0.f, 0.f, 0.f};

  {  // prologue: order A0,A1,B0,B1,B2,B3
    bf16_t* nA = lds;
    bf16_t* nB = lds + 8192;
    async16(A + srcA[0], nA + dstT);
    async16(A + srcA[1], nA + 4096 + dstT);
    async16(B + srcB[0], nB + dstT);
    async16(B + srcB[1], nB + 4096 + dstT);
    async16(B + srcB[2], nB + 8192 + dstT);
    async16(B + srcB[3], nB + 12288 + dstT);
  }
  bf16x8 af[4][2], bv0[2][2], bv1[2][2];
  for (int kt = 0; kt < nt; ++kt) {
    bf16_t* bufA = lds + (kt & 1) * 24576;
    bf16_t* bufB = bufA + 8192;
    bf16_t* nA = lds + ((kt + 1) & 1) * 24576;
    bf16_t* nB = nA + 8192;
    const int kn = (kt + 1 < nt ? kt + 1 : 0) << 6;
    const bf16_t* An = A + kn;
    const bf16_t* Bn = B + kn;
    VMW(2); BARR; FEN;
    readA8<0>(bufA, aBase, s0, s1, af);
    readB4<0>(bufB, bBase, s0, s1, bv0);
    async16(An + srcA[0], nA + dstT);
    async16(An + srcA[1], nA + 4096 + dstT);
    async16(Bn + srcB[0], nB + dstT);
    mfmaQ<4, 0, 0>(af, bv0, acc);
    VMW(3); BARR; FEN;
    readB4<1>(bufB, bBase, s0, s1, bv1);
    async16(Bn + srcB[1], nB + 4096 + dstT);
    async16(Bn + srcB[2], nB + 8192 + dstT);
    async16(Bn + srcB[3], nB + 12288 + dstT);
    mfmaQ<4, 0, 1>(af, bv1, acc);
  }
  VMW(0);
  BARR;
}

// --- elementwise convert f32 -> bf16 ---------------------------------------
__global__ void k_cvt(const float4* __restrict__ in, bf16x4* __restrict__ out, int n4) {
  int i = blockIdx.x * blockDim.x + threadIdx.x;
  if (i < n4) {
    float4 v = in[i];
    bf16x4 o;
    o[0] = (bf16_t)v.x; o[1] = (bf16_t)v.y; o[2] = (bf16_t)v.z; o[3] = (bf16_t)v.w;
    out[i] = o;
  }
}

// --- tiled transpose + convert f32[R][C] -> bf16[C][R] ----------------------
__global__ void k_tconv(const float* __restrict__ in, bf16_t* __restrict__ out,
                        int R, int C) {
  __shared__ bf16_t tile[64][65];
  int bc = blockIdx.x, br = blockIdx.y;
  int t = threadIdx.x;
  int c = t & 63, r0 = t >> 6;
#pragma unroll
  for (int rr = 0; rr < 64; rr += 4) {
    int r = rr + r0;
    tile[r][c] = (bf16_t)in[(long)(br * 64 + r) * C + bc * 64 + c];
  }
  __syncthreads();
#pragma unroll
  for (int rr = 0; rr < 64; rr += 4) {
    int r = rr + r0;
    out[(long)(bc * 64 + r) * R + br * 64 + c] = tile[c][r];
  }
}

// --- tiled transpose bf16[R][C] -> bf16[C][R], per batch (z) ----------------
__global__ void k_tbf16(const bf16_t* __restrict__ in, bf16_t* __restrict__ out,
                        int R, int C) {
  __shared__ bf16_t tile[64][65];
  long zoff = (long)blockIdx.z * R * C;
  in += zoff;
  out += zoff;
  int bc = blockIdx.x, br = blockIdx.y;
  int t = threadIdx.x;
  int c = t & 63, r0 = t >> 6;
#pragma unroll
  for (int rr = 0; rr < 64; rr += 4) {
    int r = rr + r0;
    tile[r][c] = in[(long)(br * 64 + r) * C + bc * 64 + c];
  }
  __syncthreads();
#pragma unroll
  for (int rr = 0; rr < 64; rr += 4) {
    int r = rr + r0;
    out[(long)(bc * 64 + r) * R + br * 64 + c] = tile[c][r];
  }
}

// --- GEMM1: QKVG = hsb @ Wt^T + bias (sigmoid z==3), BM=128 ----------------
__global__ __launch_bounds__(512, 2) void k_gemm_qkvg(
    const bf16_t* __restrict__ hsb, const bf16_t* __restrict__ Wt4,
    const float* __restrict__ bq, const float* __restrict__ bk,
    const float* __restrict__ bv, const float* __restrict__ bg,
    bf16_t* __restrict__ out) {
  extern __shared__ bf16_t lds[];
  // 4 rounds of 512 blocks; per round each XCD owns an 8mb x 8nb slab.
  int c = blockIdx.x;
  int r = c >> 9, xj = c & 511;
  int xcd = xj & 7, j = xj >> 3;
  int mb = r * 16 + (xcd & 1) * 8 + (j & 7);
  int nb = (xcd >> 1) * 8 + (j >> 3);
  f32x4 acc[4][4];
  core128(hsb + (long)mb * 128 * HID, HID, Wt4 + (long)nb * 256 * HID, HID,
          HID / 64, lds, acc);
  const int t = threadIdx.x, lane = t & 63, w = t >> 6;
  const int wm = w >> 2, wn = w & 3, lr = lane & 15, lg = lane >> 4;
  int z = nb >> 3;
  const float* bias = z == 0 ? bq : z == 1 ? bk : z == 2 ? bv : bg;
  int colT = (nb & 7) * 256;
  float b4[4];
#pragma unroll
  for (int nf = 0; nf < 4; ++nf) b4[nf] = bias[colT + wn * 64 + nf * 16 + lr];
  // stage C tile (128 x 256) into padded LDS
#pragma unroll
  for (int mf = 0; mf < 4; ++mf)
#pragma unroll
    for (int reg = 0; reg < 4; ++reg) {
      int lrow = wm * 64 + mf * 16 + lg * 4 + reg;
#pragma unroll
      for (int nf = 0; nf < 4; ++nf) {
        float v = acc[mf][nf][reg] + b4[nf];
        if (z == 3) v = 1.f / (1.f + __expf(-v));
        lds[lrow * SP + wn * 64 + nf * 16 + lr] = (bf16_t)v;
      }
    }
  __syncthreads();
  // coalesced copy-out: 128 rows x 512B full lines
  bf16_t* O = out + (long)z * BS * DD + (long)mb * 128 * DD + colT;
#pragma unroll
  for (int it = 0; it < 8; ++it) {
    int s = it * 512 + t;
    int rr2 = s >> 5, sg = s & 31;
    bf16x8 v = *reinterpret_cast<const bf16x8*>(&lds[rr2 * SP + sg * 8]);
    *reinterpret_cast<bf16x8*>(&O[(long)rr2 * DD + sg * 8]) = v;
  }
}

// --- pair: P[row-chunk c][jt-tile] = Q K^T; fused diag softmax, BM=128 ------
__global__ __launch_bounds__(512, 2) void k_pair(const bf16_t* __restrict__ Q,
                                                 const bf16_t* __restrict__ Kb,
                                                 bf16_t* __restrict__ P) {
  extern __shared__ bf16_t lds[];
  int p = blockIdx.x, b = blockIdx.y;
  int c = 0, base = 0;
  while (base + (c >> 1) + 1 <= p) { base += (c >> 1) + 1; ++c; }
  int jt = p - base;  // jt in [0, (c>>1)]
  f32x4 acc[4][4];
  core128(Q + ((long)b * SEQ + (long)c * 128) * DD, DD,
          Kb + ((long)b * SEQ + (long)jt * 256) * DD, DD, DD / 64, lds, acc);
  const int t = threadIdx.x, lane = t & 63, w = t >> 6;
  const int wm = w >> 2, wn = w & 3, lr = lane & 15, lg = lane >> 4;
  bf16_t* Pt = P + ((long)b * SEQ + (long)c * 128) * (long)SEQ + (long)jt * 256;
  const bool hasDiag = (jt == (c >> 1));
  const int side = c & 1;
  const float scale = 0.02209708691207961f;  // 1/sqrt(2048)
  // stage tile: raw scores; diag-chunk cols (and future cols for side==0)
  // staged as 0 (softmax overwrites the diag region directly in global).
#pragma unroll
  for (int mf = 0; mf < 4; ++mf)
#pragma unroll
    for (int reg = 0; reg < 4; ++reg) {
      int lrow = wm * 64 + mf * 16 + lg * 4 + reg;
#pragma unroll
      for (int nf = 0; nf < 4; ++nf) {
        int col = wn * 64 + nf * 16 + lr;
        float v = acc[mf][nf][reg];
        if (hasDiag && (((col >> 7) == side) || side == 0)) v = 0.f;
        lds[lrow * SP + col] = (bf16_t)v;
      }
    }
  __syncthreads();
#pragma unroll
  for (int it = 0; it < 8; ++it) {
    int s = it * 512 + t;
    int rr2 = s >> 5, sg = s & 31;
    bf16x8 v = *reinterpret_cast<const bf16x8*>(&lds[rr2 * SP + sg * 8]);
    *reinterpret_cast<bf16x8*>(&Pt[(long)rr2 * SEQ + sg * 8]) = v;
  }
  if (hasDiag) {
    VMW(0);           // copy-out stores drained before softmax overwrite
    __syncthreads();  // staging reads done before smf reuse
    float* smf = (float*)lds;
#pragma unroll
    for (int mf = 0; mf < 4; ++mf)
#pragma unroll
      for (int reg = 0; reg < 4; ++reg) {
        int row = wm * 64 + mf * 16 + lg * 4 + reg;
#pragma unroll
        for (int nf = 0; nf < 4; ++nf) {
          int col = wn * 64 + nf * 16 + lr;
          if ((col >> 7) == side) {
            int cc = col & 127;
            float sv = acc[mf][nf][reg] * scale;
            smf[row * 128 + ((cc + row) & 127)] = (cc <= row) ? sv : -1e30f;
          }
        }
      }
    __syncthreads();
    if (t < 128) {
      int r = t;
      float mx = -1e30f;
      for (int cc = 0; cc <= r; ++cc) mx = fmaxf(mx, smf[r * 128 + ((cc + r) & 127)]);
      float s = 0.f;
      for (int cc = 0; cc <= r; ++cc) s += __expf(smf[r * 128 + ((cc + r) & 127)] - mx);
      float inv = 1.f / s;
      for (int cc = 0; cc < 128; ++cc) {
        float v = (cc <= r) ? __expf(smf[r * 128 + ((cc + r) & 127)] - mx) * inv : 0.f;
        Pt[(long)r * SEQ + side * 128 + cc] = (bf16_t)v;
      }
    }
  }
}

// --- GEMM2: OutPre = (P @ V[0:K]) * gate, BM=128, longest-first -------------
__global__ __launch_bounds__(512, 2) void k_gemm2(const bf16_t* __restrict__ P,
                                                  const bf16_t* __restrict__ Vt,
                                                  const bf16_t* __restrict__ G,
                                                  bf16_t* __restrict__ OutPre) {
  extern __shared__ bf16_t lds[];
  int bid = blockIdx.x;
  int mq = 31 - (bid >> 4);  // longest-first
  int r2 = bid & 15;
  int nb = r2 >> 1, b = r2 & 1;
  f32x4 acc[4][4];
  core128(P + ((long)b * SEQ + (long)mq * 128) * (long)SEQ, SEQ,
          Vt + (long)b * DD * SEQ + (long)nb * 256 * SEQ, SEQ, (mq + 1) * 2, lds, acc);
  const int t = threadIdx.x, lane = t & 63, w = t >> 6;
  const int wm = w >> 2, wn = w & 3, lr = lane & 15, lg = lane >> 4;
  long rowb = (long)b * SEQ + (long)mq * 128;
#pragma unroll
  for (int mf = 0; mf < 4; ++mf)
#pragma unroll
    for (int reg = 0; reg < 4; ++reg) {
      int lrow = wm * 64 + mf * 16 + lg * 4 + reg;
#pragma unroll
      for (int nf = 0; nf < 4; ++nf) {
        int col = wn * 64 + nf * 16 + lr;
        float g = (float)G[(rowb + lrow) * DD + nb * 256 + col];
        lds[lrow * SP + col] = (bf16_t)(acc[mf][nf][reg] * g);
      }
    }
  __syncthreads();
  bf16_t* O = OutPre + rowb * DD + nb * 256;
#pragma unroll
  for (int it = 0; it < 8; ++it) {
    int s = it * 512 + t;
    int rr2 = s >> 5, sg = s & 31;
    bf16x8 v = *reinterpret_cast<const bf16x8*>(&lds[rr2 * SP + sg * 8]);
    *reinterpret_cast<bf16x8*>(&O[(long)rr2 * DD + sg * 8]) = v;
  }
}

// --- GEMM3: out = OutPre @ Wo + bo (f32 out, 64B segments), BM=128 ----------
__global__ __launch_bounds__(512, 2) void k_gemm3(const bf16_t* __restrict__ OutPre,
                                                  const bf16_t* __restrict__ Wot,
                                                  const float* __restrict__ bo,
                                                  float* __restrict__ out) {
  extern __shared__ bf16_t lds[];
  int mb = blockIdx.x >> 2, nb = blockIdx.x & 3;
  f32x4 acc[4][4];
  core128(OutPre + (long)mb * 128 * DD, DD, Wot + (long)nb * 256 * DD, DD,
          DD / 64, lds, acc);
  const int t = threadIdx.x, lane = t & 63, w = t >> 6;
  const int wm = w >> 2, wn = w & 3, lr = lane & 15, lg = lane >> 4;
  int colbase = nb * 256 + wn * 64;
  float b4[4];
#pragma unroll
  for (int nf = 0; nf < 4; ++nf) b4[nf] = bo[colbase + nf * 16 + lr];
#pragma unroll
  for (int mf = 0; mf < 4; ++mf)
#pragma unroll
    for (int reg = 0; reg < 4; ++reg) {
      long row = mb * 128 + wm * 64 + mf * 16 + lg * 4 + reg;
#pragma unroll
      for (int nf = 0; nf < 4; ++nf)
        out[row * HID + colbase + nf * 16 + lr] = acc[mf][nf][reg] + b4[nf];
    }
}

extern "C" void kernel_launch(void* const* d_in, const int* in_sizes, int n_in,
                              void* d_out, int out_size, void* d_ws, size_t ws_size,
                              hipStream_t stream) {
  const float* hs = (const float*)d_in[0];
  const float* Wq = (const float*)d_in[1];
  const float* bq = (const float*)d_in[2];
  const float* Wk = (const float*)d_in[3];
  const float* bk = (const float*)d_in[4];
  const float* Wv = (const float*)d_in[5];
  const float* bv = (const float*)d_in[6];
  const float* Wg = (const float*)d_in[7];
  const float* bg = (const float*)d_in[8];
  const float* Wo = (const float*)d_in[9];
  const float* bo = (const float*)d_in[10];
  float* out = (float*)d_out;

  char* ws = (char*)d_ws;
  const size_t MB = 1024 * 1024;
  bf16_t* P = (bf16_t*)(ws);
  bf16_t* hsb = (bf16_t*)(ws);
  bf16_t* Wt4 = (bf16_t*)(ws + 16 * MB);
  bf16_t* Wot = (bf16_t*)(ws + 64 * MB);
  bf16_t* QKVG = (bf16_t*)(ws + 68 * MB);
  bf16_t* Vt = (bf16_t*)(ws + 196 * MB);

  bf16_t* Qb = QKVG;
  bf16_t* Kbuf = QKVG + (long)BS * DD;
  bf16_t* Vbuf = QKVG + 2l * BS * DD;
  bf16_t* Gbuf = QKVG + 3l * BS * DD;
  bf16_t* OutPre = Vbuf;  // V row-major dead after Vt built

  hipFuncSetAttribute((const void*)k_gemm_qkvg,
                      hipFuncAttributeMaxDynamicSharedMemorySize, LDS_CORE);
  hipFuncSetAttribute((const void*)k_pair,
                      hipFuncAttributeMaxDynamicSharedMemorySize, LDS_CORE);
  hipFuncSetAttribute((const void*)k_gemm2,
                      hipFuncAttributeMaxDynamicSharedMemorySize, LDS_CORE);
  hipFuncSetAttribute((const void*)k_gemm3,
                      hipFuncAttributeMaxDynamicSharedMemorySize, LDS_CORE);

  // 1. conversions
  k_cvt<<<(BS * HID / 4 + 255) / 256, 256, 0, stream>>>((const float4*)hs,
                                                        (bf16x4*)hsb, BS * HID / 4);
  k_tconv<<<dim3(DD / 64, HID / 64), 256, 0, stream>>>(Wq, Wt4 + 0l * DD * HID, HID, DD);
  k_tconv<<<dim3(DD / 64, HID / 64), 256, 0, stream>>>(Wk, Wt4 + 1l * DD * HID, HID, DD);
  k_tconv<<<dim3(DD / 64, HID / 64), 256, 0, stream>>>(Wv, Wt4 + 2l * DD * HID, HID, DD);
  k_tconv<<<dim3(DD / 64, HID / 64), 256, 0, stream>>>(Wg, Wt4 + 3l * DD * HID, HID, DD);
  k_tconv<<<dim3(HID / 64, DD / 64), 256, 0, stream>>>(Wo, Wot, DD, HID);

  // 2. QKVG projection (BM=128: 2048 blocks, 4 rounds of per-XCD slabs)
  k_gemm_qkvg<<<2048, 512, LDS_CORE, stream>>>(hsb, Wt4, bq, bk, bv, bg, QKVG);

  // 3. V -> Vt [B][D][S]
  k_tbf16<<<dim3(DD / 64, SEQ / 64, NB_), 256, 0, stream>>>(Vbuf, Vt, SEQ, DD);

  // 4. pairwise scores + fused diag softmax
  k_pair<<<dim3(272, 2), 512, LDS_CORE, stream>>>(Qb, Kbuf, P);

  // 5. PV + gate
  k_gemm2<<<512, 512, LDS_CORE, stream>>>(P, Vt, Gbuf, OutPre);

  // 6. output projection
  k_gemm3<<<256, 512, LDS_CORE, stream>>>(OutPre, Wot, bo, out);
}